// Round 6
// baseline (455.266 us; speedup 1.0000x reference)
//
#include <hip/hip_runtime.h>
#include <stdint.h>

#define GLOBAL_AS __attribute__((address_space(1)))
#define LDS_AS    __attribute__((address_space(3)))

typedef __attribute__((ext_vector_type(8))) short short8;
typedef __attribute__((ext_vector_type(4))) float f32x4;
typedef __attribute__((ext_vector_type(4))) float float4v;
typedef __attribute__((ext_vector_type(2))) float float2v;
typedef __attribute__((ext_vector_type(4))) unsigned short ushort4v;

static constexpr int Bc = 2;
static constexpr int Lc = 512;
static constexpr int Cc = 256;
static constexpr int Pc = 128;
static constexpr int NP = Pc * Cc;               // 32768 per zj row: [p][c], c minor
static constexpr size_t TMPB = (size_t)Lc * NP;

__device__ __forceinline__ unsigned short f2bf(float x) {
  unsigned int u = __builtin_bit_cast(unsigned int, x);
  u += 0x7FFFu + ((u >> 16) & 1u);
  return (unsigned short)(u >> 16);
}

__device__ __forceinline__ void gload_lds16(const void* g, void* l) {
  __builtin_amdgcn_global_load_lds((const GLOBAL_AS unsigned int*)g,
                                   (LDS_AS unsigned int*)l, 16, 0, 0);
}

// ---- fused pre-pass ----
// blocks [0,256): w_outer [c][d][p] f32 -> wA [p][c][d] bf16 (block = c)
// blocks [256,512): single_repr f32 -> bf16 (s_bf laid out [zj][d])
__global__ void prep_kernel(const float* __restrict__ w,
                            unsigned short* __restrict__ wA,
                            const float* __restrict__ s,
                            unsigned short* __restrict__ s_bf) {
  const int t = threadIdx.x;
  if (blockIdx.x >= 256) {
    const int idx = ((blockIdx.x - 256) * 256 + t) * 4;
    float4v v = *(const float4v*)&s[idx];
    ushort4v o;
    #pragma unroll
    for (int i = 0; i < 4; ++i) o[i] = f2bf(v[i]);
    *(ushort4v*)&s_bf[idx] = o;
    return;
  }
  __shared__ unsigned short lds[128 * 258];
  const int c = blockIdx.x;
  const float* wc = w + (size_t)c * (Cc * Pc);
  #pragma unroll 4
  for (int it = 0; it < 128; ++it) {
    const int idx = it * 256 + t;        // idx = d*128 + p
    const int d = idx >> 7, p = idx & 127;
    lds[p * 258 + d] = f2bf(wc[idx]);
  }
  __syncthreads();
  #pragma unroll 4
  for (int it = 0; it < 128; ++it) {
    const int idx = it * 256 + t;        // idx = p*256 + d
    const int p = idx >> 8, d = idx & 255;
    wA[(size_t)p * 65536 + (size_t)c * 256 + d] = lds[p * 258 + d];
  }
}

// ---- shared 256x256-tile, BK=64, K=256, 8-wave core ----
// v2: (a) XOR-swizzled LDS layout: 16B slot (row, s) holds global chunk
//     (row, s ^ (row&7)); achieved by pre-swizzling the GLOBAL source column
//     (LDS dest stays linear, as global_load_lds requires) and XOR-ing the
//     ds_read slot. Spreads fragment reads over all 32 banks (was: 16 rows
//     on one 4-bank group = half banks idle).
//     (b) counted-vmcnt 2-barrier loop: prefetch's 8 global_load_lds stay in
//     flight across barriers (s_waitcnt vmcnt(8), never 0 in main loop).
__device__ __forceinline__ void run_gemm_k256(
    const unsigned short* __restrict__ gA,
    const unsigned short* __restrict__ gB,
    unsigned short (&As)[2][256 * 64],
    unsigned short (&Bs)[2][256 * 64],
    const int tid, const int wave, const int wr, const int wc,
    const int lr, const int lk,
    f32x4 (&acc)[8][4]) {
  const int grow = tid >> 3;                          // row within 64-row chunk
  const int swz  = ((tid & 7) ^ (grow & 7)) << 3;     // swizzled k-offset (elems)

  auto stage = [&](int sel, int t) {
    const int k0 = t * 64 + swz;
    #pragma unroll
    for (int r = 0; r < 4; ++r) {
      const int row = r * 64 + grow;
      gload_lds16(&gA[(size_t)row * 256 + k0],
                  &As[sel][(size_t)(r * 512 + wave * 64) * 8]);
    }
    #pragma unroll
    for (int r = 0; r < 4; ++r) {
      const int row = r * 64 + grow;
      gload_lds16(&gB[(size_t)row * 256 + k0],
                  &Bs[sel][(size_t)(r * 512 + wave * 64) * 8]);
    }
  };

  // read-side swizzled slot offsets (elems) for kk=0,1; row&7 == lr&7 since
  // all row terms except lr are multiples of 8/16.
  const int hi = lk >> 3;                 // lane>>4
  const int xr = lr & 7;
  const int ro0 = (((0 * 4) + hi) ^ xr) << 3;
  const int ro1 = (((1 * 4) + hi) ^ xr) << 3;

  stage(0, 0);
  asm volatile("s_waitcnt vmcnt(0)" ::: "memory");
  __builtin_amdgcn_s_barrier();

  #pragma unroll
  for (int t = 0; t < 4; ++t) {
    const int cur = t & 1;
    if (t < 3) {
      stage(cur ^ 1, t + 1);                          // 8 loads in flight
      asm volatile("s_waitcnt vmcnt(8)" ::: "memory"); // wait only for cur tile
    } else {
      asm volatile("s_waitcnt vmcnt(0)" ::: "memory");
    }
    __builtin_amdgcn_s_barrier();                     // cur staged on all waves
    __builtin_amdgcn_sched_barrier(0);
    #pragma unroll
    for (int kk = 0; kk < 2; ++kk) {
      const int ro = kk ? ro1 : ro0;
      short8 a[8], b[4];
      #pragma unroll
      for (int m = 0; m < 8; ++m)
        a[m] = *(const short8*)&As[cur][(wr * 128 + m * 16 + lr) * 64 + ro];
      #pragma unroll
      for (int n = 0; n < 4; ++n)
        b[n] = *(const short8*)&Bs[cur][(wc * 64 + n * 16 + lr) * 64 + ro];
      #pragma unroll
      for (int m = 0; m < 8; ++m)
        #pragma unroll
        for (int n = 0; n < 4; ++n)
          acc[m][n] = __builtin_amdgcn_mfma_f32_16x16x32_bf16(a[m], b[n], acc[m][n], 0, 0, 0);
    }
    if (t < 3) {
      asm volatile("s_waitcnt lgkmcnt(0)" ::: "memory"); // our reads retired
      __builtin_amdgcn_s_barrier();                      // before cur is overwritten
    }
  }
}

// ---- GEMM 1: tmpT[zj][p][c] = sum_d s_bf[zj,d] * wA[p][c][d] ----
__global__ __launch_bounds__(512, 2) void gemm1_k(
    const unsigned short* __restrict__ sbf,
    const unsigned short* __restrict__ wA,
    unsigned short* __restrict__ tmpT) {
  __shared__ unsigned short As[2][256 * 64];
  __shared__ unsigned short Bs[2][256 * 64];
  const int tid = threadIdx.x;
  const int wave = tid >> 6, lane = tid & 63;
  const int wr = wave >> 2, wc = wave & 3;
  const int lr = lane & 15, lk = (lane >> 4) << 3;

  const int bid = blockIdx.x;                  // 512 = 8 * 64
  const int f = (bid & 7) * 64 + (bid >> 3);   // chunked XCD assignment
  const int p = f >> 2, nt = f & 3;

  const unsigned short* gA = wA + (size_t)p * 65536;
  const unsigned short* gB = sbf + (size_t)nt * 65536;

  f32x4 acc[8][4];
  const f32x4 zero = {0.f, 0.f, 0.f, 0.f};
  #pragma unroll
  for (int m = 0; m < 8; ++m)
    #pragma unroll
    for (int n = 0; n < 4; ++n) acc[m][n] = zero;

  run_gemm_k256(gA, gB, As, Bs, tid, wave, wr, wc, lr, lk, acc);

  const int cq = wr * 128 + ((lane >> 4) << 2);
  #pragma unroll
  for (int n = 0; n < 4; ++n) {
    const int zj = nt * 256 + wc * 64 + n * 16 + lr;
    unsigned short* dst = tmpT + (size_t)zj * NP + p * 256 + cq;
    #pragma unroll
    for (int m = 0; m < 8; ++m) {
      ushort4v o;
      #pragma unroll
      for (int q = 0; q < 4; ++q) o[q] = f2bf(acc[m][n][q]);
      *(ushort4v*)&dst[m * 16] = o;
    }
  }
}

// ---- GEMM 2 + epilogue: out[z,i,j,p] = sum_c s_bf[z*512+i,c]*tmpT[z*512+j][p][c] ----
__global__ __launch_bounds__(512, 2) void gemm2_k(
    const unsigned short* __restrict__ sbf,
    const unsigned short* __restrict__ tmpT,
    const float* __restrict__ pair_bias,
    const float* __restrict__ mask,
    const float* __restrict__ b_outer,
    const float* __restrict__ pos_embed,
    const float* __restrict__ w_bias,
    const float* __restrict__ b_bias,
    float* __restrict__ out) {
  __shared__ unsigned short As[2][256 * 64];
  __shared__ unsigned short Bs[2][256 * 64];
  const int tid = threadIdx.x;
  const int wave = tid >> 6, lane = tid & 63;
  const int wr = wave >> 2, wc = wave & 3;
  const int lr = lane & 15, lk = (lane >> 4) << 3;

  const int bid = blockIdx.x;                   // 1024 = 8 * 128
  const int f = (bid & 7) * 128 + (bid >> 3);   // chunked XCD assignment
  const int jt = f >> 1, i0t = f & 1;
  const int z = jt >> 8;

  const unsigned short* gA = tmpT + (size_t)jt * 65536;   // 2 zj rows x [p][c]
  const unsigned short* gB = sbf + (size_t)(z * Lc + i0t * 256) * Cc;

  f32x4 acc[8][4];
  const f32x4 zero = {0.f, 0.f, 0.f, 0.f};
  #pragma unroll
  for (int m = 0; m < 8; ++m)
    #pragma unroll
    for (int n = 0; n < 4; ++n) acc[m][n] = zero;

  run_gemm_k256(gA, gB, As, Bs, tid, wave, wr, wc, lr, lk, acc);

  // epilogue: wave owns zj = jt*2 + wr, all 128 p, 64 i
  const int zj = jt * 2 + wr;
  const int j = zj & (Lc - 1);
  const int pq = (lane >> 4) << 2;
  const float mj = mask[z * Lc + j];

  float4v base8[8];
  #pragma unroll
  for (int m = 0; m < 8; ++m) {
    const int pp = m * 16 + pq;
    base8[m] = *(const float4v*)&b_outer[pp] + *(const float4v*)&b_bias[pp];
  }

  #pragma unroll
  for (int n = 0; n < 4; ++n) {
    const int i = i0t * 256 + wc * 64 + n * 16 + lr;
    const float sc = mask[z * Lc + i] * mj;
    const size_t rowoff = ((size_t)(z * Lc + i)) * Lc + j;
    const float2v pb = *(const float2v*)&pair_bias[rowoff * 2];
    int rel = i - j;
    rel = rel < -15 ? -15 : (rel > 15 ? 15 : rel);
    rel += 15;
    const float* pe_row = pos_embed + rel * Pc;
    float* drow = out + rowoff * Pc;
    #pragma unroll
    for (int m = 0; m < 8; ++m) {
      const int pp = m * 16 + pq;
      const float4v wb0 = *(const float4v*)&w_bias[pp];
      const float4v wb1 = *(const float4v*)&w_bias[Pc + pp];
      const float4v pe4 = *(const float4v*)&pe_row[pp];
      float4v v = acc[m][n] + base8[m] + pb[0] * wb0 + pb[1] * wb1 + pe4;
      *(float4v*)&drow[pp] = v * sc;
    }
  }
}

extern "C" void kernel_launch(void* const* d_in, const int* in_sizes, int n_in,
                              void* d_out, int out_size, void* d_ws, size_t ws_size,
                              hipStream_t stream) {
  const float* s         = (const float*)d_in[0];
  const float* pair_bias = (const float*)d_in[1];
  const float* mask      = (const float*)d_in[2];
  const float* w_outer   = (const float*)d_in[3];
  const float* b_outer   = (const float*)d_in[4];
  const float* pos_embed = (const float*)d_in[5];
  const float* w_bias    = (const float*)d_in[6];
  const float* b_bias    = (const float*)d_in[7];
  float* out = (float*)d_out;

  unsigned char* ws = (unsigned char*)d_ws;
  unsigned short* s_bf = (unsigned short*)ws;                          // 512 KB
  unsigned short* wA   = (unsigned short*)(ws + (512u << 10));         // 16 MB
  unsigned short* tmpT = (unsigned short*)(ws + (512u << 10) + (16u << 20)); // 67 MB

  prep_kernel<<<512, 256, 0, stream>>>(w_outer, wA, s, s_bf);
  gemm1_k<<<512, 512, 0, stream>>>(s_bf, wA, tmpT);
  gemm2_k<<<1024, 512, 0, stream>>>(s_bf, tmpT, pair_bias, mask,
                                    b_outer, pos_embed, w_bias, b_bias, out);
}

// Round 7
// 427.887 us; speedup vs baseline: 1.0640x; 1.0640x over previous
//
#include <hip/hip_runtime.h>
#include <stdint.h>

#define GLOBAL_AS __attribute__((address_space(1)))
#define LDS_AS    __attribute__((address_space(3)))

typedef __attribute__((ext_vector_type(8))) short short8;
typedef __attribute__((ext_vector_type(4))) float f32x4;
typedef __attribute__((ext_vector_type(4))) float float4v;
typedef __attribute__((ext_vector_type(2))) float float2v;
typedef __attribute__((ext_vector_type(4))) unsigned short ushort4v;

static constexpr int Bc = 2;
static constexpr int Lc = 512;
static constexpr int Cc = 256;
static constexpr int Pc = 128;
static constexpr int NP = Pc * Cc;               // 32768 per zj row: [p][c], c minor
static constexpr size_t TMPB = (size_t)Lc * NP;

__device__ __forceinline__ unsigned short f2bf(float x) {
  unsigned int u = __builtin_bit_cast(unsigned int, x);
  u += 0x7FFFu + ((u >> 16) & 1u);
  return (unsigned short)(u >> 16);
}

__device__ __forceinline__ void gload_lds16(const void* g, void* l) {
  __builtin_amdgcn_global_load_lds((const GLOBAL_AS unsigned int*)g,
                                   (LDS_AS unsigned int*)l, 16, 0, 0);
}

// ---- fused pre-pass ----
// blocks [0,256): w_outer [c][d][p] f32 -> wA [p][c][d] bf16 (block = c)
// blocks [256,512): single_repr f32 -> bf16 (s_bf laid out [zj][d])
__global__ void prep_kernel(const float* __restrict__ w,
                            unsigned short* __restrict__ wA,
                            const float* __restrict__ s,
                            unsigned short* __restrict__ s_bf) {
  const int t = threadIdx.x;
  if (blockIdx.x >= 256) {
    const int idx = ((blockIdx.x - 256) * 256 + t) * 4;
    float4v v = *(const float4v*)&s[idx];
    ushort4v o;
    #pragma unroll
    for (int i = 0; i < 4; ++i) o[i] = f2bf(v[i]);
    *(ushort4v*)&s_bf[idx] = o;
    return;
  }
  __shared__ unsigned short lds[128 * 258];
  const int c = blockIdx.x;
  const float* wc = w + (size_t)c * (Cc * Pc);
  #pragma unroll 4
  for (int it = 0; it < 128; ++it) {
    const int idx = it * 256 + t;        // idx = d*128 + p
    const int d = idx >> 7, p = idx & 127;
    lds[p * 258 + d] = f2bf(wc[idx]);
  }
  __syncthreads();
  #pragma unroll 4
  for (int it = 0; it < 128; ++it) {
    const int idx = it * 256 + t;        // idx = p*256 + d
    const int p = idx >> 8, d = idx & 255;
    wA[(size_t)p * 65536 + (size_t)c * 256 + d] = lds[p * 258 + d];
  }
}

// ---- shared 128x128-tile, BK=64, K=256, 4-wave, single-buffer m97 core ----
// 32 KiB LDS -> ~3 blocks/CU; inter-block wave overlap (m114) hides the
// barrier drains that an explicit dbuf cannot at 1 block/CU.
__device__ __forceinline__ void run_gemm128_k256(
    const unsigned short* __restrict__ gA,   // 128 rows x 256, row-major
    const unsigned short* __restrict__ gB,   // 128 rows x 256, row-major
    unsigned short (&As)[128 * 64],
    unsigned short (&Bs)[128 * 64],
    const int tid, const int wave, const int wr, const int wcn,
    const int lr, const int lk,
    f32x4 (&acc)[4][4]) {
  #pragma unroll 1
  for (int kt = 0; kt < 4; ++kt) {
    const int k0 = kt * 64;
    __syncthreads();
    #pragma unroll
    for (int op = 0; op < 4; ++op) {
      const int idx = op * 256 + tid;
      const int row = idx >> 3, col = (idx & 7) << 3;
      gload_lds16(&gA[(size_t)row * 256 + k0 + col],
                  &As[(size_t)(op * 256 + wave * 64) * 8]);
    }
    #pragma unroll
    for (int op = 0; op < 4; ++op) {
      const int idx = op * 256 + tid;
      const int row = idx >> 3, col = (idx & 7) << 3;
      gload_lds16(&gB[(size_t)row * 256 + k0 + col],
                  &Bs[(size_t)(op * 256 + wave * 64) * 8]);
    }
    __syncthreads();
    #pragma unroll
    for (int kk = 0; kk < 2; ++kk) {
      short8 a[4], b[4];
      #pragma unroll
      for (int m = 0; m < 4; ++m)
        a[m] = *(const short8*)&As[(wr * 64 + m * 16 + lr) * 64 + kk * 32 + lk];
      #pragma unroll
      for (int n = 0; n < 4; ++n)
        b[n] = *(const short8*)&Bs[(wcn * 64 + n * 16 + lr) * 64 + kk * 32 + lk];
      #pragma unroll
      for (int m = 0; m < 4; ++m)
        #pragma unroll
        for (int n = 0; n < 4; ++n)
          acc[m][n] = __builtin_amdgcn_mfma_f32_16x16x32_bf16(a[m], b[n], acc[m][n], 0, 0, 0);
    }
  }
}

// ---- GEMM 1: tmpT[zj][p][c] = sum_d s_bf[zj,d] * wA[p][c][d] ----
// M = 32768 flat (p,c) -> 256 M-tiles; N = 1024 zj -> 8 N-tiles.
// flat f = mt*8 + nt; chunked-XCD: the 8 nt-sharers of each 64 KB wA panel
// sit adjacent on one XCD (grid 2048 = 8 XCD x 256).
__global__ __launch_bounds__(256) void gemm1_k(
    const unsigned short* __restrict__ sbf,
    const unsigned short* __restrict__ wA,
    unsigned short* __restrict__ tmpT) {
  __shared__ unsigned short As[128 * 64];
  __shared__ unsigned short Bs[128 * 64];
  const int tid = threadIdx.x;
  const int wave = tid >> 6, lane = tid & 63;
  const int wr = wave >> 1, wcn = wave & 1;
  const int lr = lane & 15, lk = (lane >> 4) << 3;

  const int bid = blockIdx.x;                    // 2048 = 8 * 256
  const int f = (bid & 7) * 256 + (bid >> 3);    // chunked XCD assignment
  const int mt = f >> 3, nt = f & 7;

  const unsigned short* gA = wA + (size_t)mt * 32768;       // 128 (p,c) rows
  const unsigned short* gB = sbf + (size_t)nt * 128 * 256;  // 128 zj rows

  f32x4 acc[4][4];
  const f32x4 zero = {0.f, 0.f, 0.f, 0.f};
  #pragma unroll
  for (int m = 0; m < 4; ++m)
    #pragma unroll
    for (int n = 0; n < 4; ++n) acc[m][n] = zero;

  run_gemm128_k256(gA, gB, As, Bs, tid, wave, wr, wcn, lr, lk, acc);

  const int rbase = wr * 64 + ((lane >> 4) << 2);   // local (p,c) row base
  #pragma unroll
  for (int n = 0; n < 4; ++n) {
    const int zj = nt * 128 + wcn * 64 + n * 16 + lr;
    unsigned short* dst = tmpT + (size_t)zj * NP + mt * 128 + rbase;
    #pragma unroll
    for (int m = 0; m < 4; ++m) {
      ushort4v o;
      #pragma unroll
      for (int q = 0; q < 4; ++q) o[q] = f2bf(acc[m][n][q]);
      *(ushort4v*)&dst[m * 16] = o;
    }
  }
}

// ---- GEMM 2 + epilogue: out[z,i,j,p] = sum_c s_bf[z*512+i,c]*tmpT[zj][p][c] ----
// M-tile = one zj (128 p-rows); N = 512 i per z -> 4 N-tiles.
// flat f = zj*4 + nt; chunked-XCD: the 4 nt-sharers of each 64 KB tmpT panel
// (and the 8 zj-neighbors sharing pair_bias lines) sit on one XCD.
__global__ __launch_bounds__(256) void gemm2_k(
    const unsigned short* __restrict__ sbf,
    const unsigned short* __restrict__ tmpT,
    const float* __restrict__ pair_bias,
    const float* __restrict__ mask,
    const float* __restrict__ b_outer,
    const float* __restrict__ pos_embed,
    const float* __restrict__ w_bias,
    const float* __restrict__ b_bias,
    float* __restrict__ out) {
  __shared__ unsigned short As[128 * 64];
  __shared__ unsigned short Bs[128 * 64];
  const int tid = threadIdx.x;
  const int wave = tid >> 6, lane = tid & 63;
  const int wr = wave >> 1, wcn = wave & 1;
  const int lr = lane & 15, lk = (lane >> 4) << 3;

  const int bid = blockIdx.x;                    // 4096 = 8 * 512
  const int f = (bid & 7) * 512 + (bid >> 3);    // chunked XCD assignment
  const int zj = f >> 2, nt = f & 3;
  const int z = zj >> 9;
  const int j = zj & (Lc - 1);

  const unsigned short* gA = tmpT + (size_t)zj * NP;              // 128 p-rows
  const unsigned short* gB = sbf + ((size_t)(z * Lc) + nt * 128) * Cc;

  f32x4 acc[4][4];
  const f32x4 zero = {0.f, 0.f, 0.f, 0.f};
  #pragma unroll
  for (int m = 0; m < 4; ++m)
    #pragma unroll
    for (int n = 0; n < 4; ++n) acc[m][n] = zero;

  run_gemm128_k256(gA, gB, As, Bs, tid, wave, wr, wcn, lr, lk, acc);

  // D: row = p (q-contiguous), col = i
  const int pbase = wr * 64 + ((lane >> 4) << 2);
  const float mj = mask[z * Lc + j];

  float4v base4[4], wb0v[4], wb1v[4];
  #pragma unroll
  for (int m = 0; m < 4; ++m) {
    const int pp = pbase + m * 16;
    base4[m] = *(const float4v*)&b_outer[pp] + *(const float4v*)&b_bias[pp];
    wb0v[m] = *(const float4v*)&w_bias[pp];
    wb1v[m] = *(const float4v*)&w_bias[Pc + pp];
  }

  #pragma unroll
  for (int n = 0; n < 4; ++n) {
    const int i = nt * 128 + wcn * 64 + n * 16 + lr;
    const float sc = mask[z * Lc + i] * mj;
    const size_t rowoff = ((size_t)(z * Lc + i)) * Lc + j;
    const float2v pb = *(const float2v*)&pair_bias[rowoff * 2];
    int rel = i - j;
    rel = rel < -15 ? -15 : (rel > 15 ? 15 : rel);
    rel += 15;
    const float* pe_row = pos_embed + rel * Pc;
    float* drow = out + rowoff * Pc;
    #pragma unroll
    for (int m = 0; m < 4; ++m) {
      const int pp = pbase + m * 16;
      const float4v pe4 = *(const float4v*)&pe_row[pp];
      float4v v = acc[m][n] + base4[m] + pb[0] * wb0v[m] + pb[1] * wb1v[m] + pe4;
      *(float4v*)&drow[pp] = v * sc;
    }
  }
}

extern "C" void kernel_launch(void* const* d_in, const int* in_sizes, int n_in,
                              void* d_out, int out_size, void* d_ws, size_t ws_size,
                              hipStream_t stream) {
  const float* s         = (const float*)d_in[0];
  const float* pair_bias = (const float*)d_in[1];
  const float* mask      = (const float*)d_in[2];
  const float* w_outer   = (const float*)d_in[3];
  const float* b_outer   = (const float*)d_in[4];
  const float* pos_embed = (const float*)d_in[5];
  const float* w_bias    = (const float*)d_in[6];
  const float* b_bias    = (const float*)d_in[7];
  float* out = (float*)d_out;

  unsigned char* ws = (unsigned char*)d_ws;
  unsigned short* s_bf = (unsigned short*)ws;                          // 512 KB
  unsigned short* wA   = (unsigned short*)(ws + (512u << 10));         // 16 MB
  unsigned short* tmpT = (unsigned short*)(ws + (512u << 10) + (16u << 20)); // 67 MB

  prep_kernel<<<512, 256, 0, stream>>>(w_outer, wA, s, s_bf);
  gemm1_k<<<2048, 256, 0, stream>>>(s_bf, wA, tmpT);
  gemm2_k<<<4096, 256, 0, stream>>>(s_bf, tmpT, pair_bias, mask,
                                    b_outer, pos_embed, w_bias, b_bias, out);
}